// Round 1
// baseline (2455.210 us; speedup 1.0000x reference)
//
#include <hip/hip_runtime.h>
#include <hip/hip_bf16.h>
#include <math.h>

#define BB 8
#define SS 1024
#define DD 512
#define HH 8
#define DQQ 64

// ---------------- LayerNorm: one block per row ----------------
__global__ __launch_bounds__(256) void ln_kernel(const float* __restrict__ x,
                                                 const float* __restrict__ g,
                                                 const float* __restrict__ b,
                                                 float* __restrict__ xn) {
    int row = blockIdx.x;
    int tid = threadIdx.x;
    const float* xr = x + (size_t)row * DD;
    float v0 = xr[tid], v1 = xr[tid + 256];
    float s = v0 + v1;
    float ss = v0 * v0 + v1 * v1;
    for (int off = 32; off; off >>= 1) {
        s += __shfl_down(s, off);
        ss += __shfl_down(ss, off);
    }
    __shared__ float ps[4], pss[4];
    int wid = tid >> 6, lane = tid & 63;
    if (lane == 0) { ps[wid] = s; pss[wid] = ss; }
    __syncthreads();
    float tot_s = ps[0] + ps[1] + ps[2] + ps[3];
    float tot_ss = pss[0] + pss[1] + pss[2] + pss[3];
    float mu = tot_s * (1.0f / DD);
    float var = tot_ss * (1.0f / DD) - mu * mu;
    float inv = rsqrtf(var + 1e-5f);
    float* xo = xn + (size_t)row * DD;
    xo[tid] = (v0 - mu) * inv * g[tid] + b[tid];
    xo[tid + 256] = (v1 - mu) * inv * g[tid + 256] + b[tid + 256];
}

// ---------------- Projection GEMM: C[8192,512] = A @ W + bias ----------------
// MODE 0: scatter to [B,H,S,64] layout (for K/V). MODE 1: linear + residual (final out).
template <int MODE>
__global__ __launch_bounds__(256) void proj_kernel(const float* __restrict__ A,
                                                   const float* __restrict__ W,
                                                   const float* __restrict__ bias,
                                                   const float* __restrict__ resid,
                                                   float* __restrict__ out) {
    __shared__ float As[8 * 512];
    int tid = threadIdx.x;
    int row0 = blockIdx.x * 8;
    const float* Ab = A + (size_t)row0 * DD;
    for (int idx = tid; idx < 8 * 512; idx += 256) As[idx] = Ab[idx];
    __syncthreads();
    int c0 = tid, c1 = tid + 256;
    float acc0[8], acc1[8];
    float b0 = bias[c0], b1 = bias[c1];
#pragma unroll
    for (int r = 0; r < 8; ++r) { acc0[r] = b0; acc1[r] = b1; }
    for (int k = 0; k < 512; ++k) {
        float w0 = W[(size_t)k * 512 + c0];
        float w1 = W[(size_t)k * 512 + c1];
#pragma unroll
        for (int r = 0; r < 8; ++r) {
            float a = As[r * 512 + k];
            acc0[r] = fmaf(a, w0, acc0[r]);
            acc1[r] = fmaf(a, w1, acc1[r]);
        }
    }
#pragma unroll
    for (int r = 0; r < 8; ++r) {
        int R = row0 + r;
        if (MODE == 0) {
            int b = R >> 10, sidx = R & 1023;
            int h0 = c0 >> 6, d0 = c0 & 63;
            int h1 = c1 >> 6, d1 = c1 & 63;
            out[(((size_t)(b * HH + h0)) * SS + sidx) * 64 + d0] = acc0[r];
            out[(((size_t)(b * HH + h1)) * SS + sidx) * 64 + d1] = acc1[r];
        } else {
            out[(size_t)R * 512 + c0] = acc0[r] + resid[(size_t)R * 512 + c0];
            out[(size_t)R * 512 + c1] = acc1[r] + resid[(size_t)R * 512 + c1];
        }
    }
}

// ---------------- bias table: biasS[q,k] = (pos[q,k,:]@wp + bp) / sqrt(DQ) ----------------
__global__ __launch_bounds__(256) void bias_kernel(const float* __restrict__ pos,
                                                   const float* __restrict__ wp,
                                                   const float* __restrict__ bp,
                                                   float* __restrict__ biasS) {
    int idx = blockIdx.x * 256 + threadIdx.x;  // 0 .. 1048575
    const float4* p4 = (const float4*)(pos + (size_t)idx * 32);
    const float4* w4 = (const float4*)wp;
    float dot = 0.f;
#pragma unroll
    for (int j = 0; j < 8; ++j) {
        float4 pv = p4[j];
        float4 wv = w4[j];
        dot += pv.x * wv.x + pv.y * wv.y + pv.z * wv.z + pv.w * wv.w;
    }
    biasS[idx] = (dot + bp[0]) * 0.125f;
}

// ---------------- attention: per (b,h, 8-q tile) ----------------
__global__ __launch_bounds__(256) void attn_kernel(const float* __restrict__ K,
                                                   const float* __restrict__ V,
                                                   const float* __restrict__ biasS,
                                                   const float* __restrict__ wp,
                                                   const int* __restrict__ lens,
                                                   float* __restrict__ probs,
                                                   float* __restrict__ O) {
    __shared__ float Kq[8 * 64];
    __shared__ float Kc[64 * 65];
    __shared__ float Pb[8 * 1024];
    int tid = threadIdx.x;
    int qt = blockIdx.x & 127;
    int bh = blockIdx.x >> 7;
    int b = bh >> 3, h = bh & 7;
    int len = lens[b];
    const float* Kb = K + (size_t)bh * SS * 64;
    const float* Vb = V + (size_t)bh * SS * 64;

    float swp = 0.f;
#pragma unroll
    for (int p = 0; p < 32; ++p) swp += wp[p];
    const float c = swp * 0.044194173824159216f;  // 1/(8*sqrt(8)) = 1/(sqrt(H)*sqrt(DQ))

    for (int idx = tid; idx < 512; idx += 256) Kq[idx] = Kb[(size_t)qt * 512 + idx];

    // ----- scores -----
    for (int kc = 0; kc < 16; ++kc) {
        __syncthreads();
        for (int idx = tid; idx < 4096; idx += 256)
            Kc[(idx >> 6) * 65 + (idx & 63)] = Kb[(size_t)kc * 4096 + idx];
        __syncthreads();
#pragma unroll
        for (int i = 0; i < 2; ++i) {
            int pair = tid + 256 * i;
            int q = pair >> 6;
            int kl = pair & 63;
            const float* kqr = Kq + q * 64;
            const float* kcr = Kc + kl * 65;
            float dot = 0.f;
#pragma unroll
            for (int d = 0; d < 64; ++d) dot = fmaf(kqr[d], kcr[d], dot);
            int kg = kc * 64 + kl;
            int qg = qt * 8 + q;
            float sc = dot * c + biasS[(size_t)qg * 1024 + kg];
            if (kg >= len) sc = -INFINITY;
            Pb[q * 1024 + kg] = sc;
        }
    }
    __syncthreads();

    // ----- softmax: wave w handles rows 2w, 2w+1; write probs to global -----
    int wid = tid >> 6, lane = tid & 63;
    float* probsBase = probs + ((size_t)bh * SS + (size_t)qt * 8) * SS;
    for (int rr = 0; rr < 2; ++rr) {
        int r = wid * 2 + rr;
        float* Pr = Pb + r * 1024;
        float m = -INFINITY;
#pragma unroll
        for (int j = 0; j < 16; ++j) m = fmaxf(m, Pr[lane + 64 * j]);
        for (int off = 32; off; off >>= 1) m = fmaxf(m, __shfl_xor(m, off));
        float sum = 0.f;
#pragma unroll
        for (int j = 0; j < 16; ++j) {
            float e = __expf(Pr[lane + 64 * j] - m);
            Pr[lane + 64 * j] = e;
            sum += e;
        }
        for (int off = 32; off; off >>= 1) sum += __shfl_xor(sum, off);
        float inv = 1.f / sum;
#pragma unroll
        for (int j = 0; j < 16; ++j) {
            float pv = Pr[lane + 64 * j] * inv;
            Pr[lane + 64 * j] = pv;
            probsBase[(size_t)r * SS + lane + 64 * j] = pv;
        }
    }
    __syncthreads();

    // ----- PV -----
    float acc[2] = {0.f, 0.f};
    for (int kc = 0; kc < 16; ++kc) {
        __syncthreads();
        for (int idx = tid; idx < 4096; idx += 256)
            Kc[(idx >> 6) * 65 + (idx & 63)] = Vb[(size_t)kc * 4096 + idx];
        __syncthreads();
#pragma unroll
        for (int i = 0; i < 2; ++i) {
            int pair = tid + 256 * i;
            int q = pair >> 6;
            int d = pair & 63;
            float a = acc[i];
            const float* Pr = Pb + q * 1024 + kc * 64;
            const float* Vr = Kc + d;
#pragma unroll
            for (int kl = 0; kl < 64; ++kl) a = fmaf(Pr[kl], Vr[kl * 65], a);
            acc[i] = a;
        }
    }
#pragma unroll
    for (int i = 0; i < 2; ++i) {
        int pair = tid + 256 * i;
        int q = pair >> 6;
        int d = pair & 63;
        int qg = qt * 8 + q;
        O[((size_t)(b * SS + qg)) * 512 + h * 64 + d] = acc[i];
    }
}

extern "C" void kernel_launch(void* const* d_in, const int* in_sizes, int n_in,
                              void* d_out, int out_size, void* d_ws, size_t ws_size,
                              hipStream_t stream) {
    const float* x    = (const float*)d_in[0];
    const float* ln_g = (const float*)d_in[1];
    const float* ln_b = (const float*)d_in[2];
    const float* Wk   = (const float*)d_in[3];
    const float* bk   = (const float*)d_in[4];
    const float* Wv   = (const float*)d_in[5];
    const float* bv   = (const float*)d_in[6];
    const float* pos  = (const float*)d_in[7];
    const float* wp   = (const float*)d_in[8];
    const float* bp   = (const float*)d_in[9];
    const float* Wo   = (const float*)d_in[10];
    const float* bo   = (const float*)d_in[11];
    const int* lens   = (const int*)d_in[12];

    float* out_seq = (float*)d_out;                  // 8*1024*512 = 4194304
    float* out_probs = out_seq + 4194304;            // 8*8*1024*1024

    float* ws    = (float*)d_ws;
    float* xn    = ws;                    // 4194304
    float* Kbuf  = xn + 4194304;          // 4194304
    float* Vbuf  = Kbuf + 4194304;        // 4194304
    float* biasS = Vbuf + 4194304;        // 1048576
    float* Obuf  = biasS + 1048576;       // 4194304

    ln_kernel<<<8192, 256, 0, stream>>>(x, ln_g, ln_b, xn);
    proj_kernel<0><<<1024, 256, 0, stream>>>(xn, Wk, bk, nullptr, Kbuf);
    proj_kernel<0><<<1024, 256, 0, stream>>>(xn, Wv, bv, nullptr, Vbuf);
    bias_kernel<<<4096, 256, 0, stream>>>(pos, wp, bp, biasS);
    attn_kernel<<<8192, 256, 0, stream>>>(Kbuf, Vbuf, biasS, wp, lens, out_probs, Obuf);
    proj_kernel<1><<<1024, 256, 0, stream>>>(Obuf, Wo, bo, x, out_seq);
}

// Round 2
// 735.724 us; speedup vs baseline: 3.3371x; 3.3371x over previous
//
#include <hip/hip_runtime.h>
#include <hip/hip_bf16.h>
#include <math.h>

typedef __attribute__((ext_vector_type(8))) short short8;
typedef __attribute__((ext_vector_type(4))) float f32x4;

#define SS 1024
#define DD 512
#define HH 8

__device__ __forceinline__ unsigned short f2bf(float f) {
    unsigned u; __builtin_memcpy(&u, &f, 4);
    u = (u + 0x7FFFu + ((u >> 16) & 1u)) >> 16;
    return (unsigned short)u;
}

// ---------------- LayerNorm: one block per row ----------------
__global__ __launch_bounds__(256) void ln_kernel(const float* __restrict__ x,
                                                 const float* __restrict__ g,
                                                 const float* __restrict__ b,
                                                 float* __restrict__ xn) {
    int row = blockIdx.x;
    int tid = threadIdx.x;
    const float* xr = x + (size_t)row * DD;
    float v0 = xr[tid], v1 = xr[tid + 256];
    float s = v0 + v1;
    float ss = v0 * v0 + v1 * v1;
    for (int off = 32; off; off >>= 1) {
        s += __shfl_down(s, off);
        ss += __shfl_down(ss, off);
    }
    __shared__ float ps[4], pss[4];
    int wid = tid >> 6, lane = tid & 63;
    if (lane == 0) { ps[wid] = s; pss[wid] = ss; }
    __syncthreads();
    float tot_s = ps[0] + ps[1] + ps[2] + ps[3];
    float tot_ss = pss[0] + pss[1] + pss[2] + pss[3];
    float mu = tot_s * (1.0f / DD);
    float var = tot_ss * (1.0f / DD) - mu * mu;
    float inv = rsqrtf(var + 1e-5f);
    float* xo = xn + (size_t)row * DD;
    xo[tid] = (v0 - mu) * inv * g[tid] + b[tid];
    xo[tid + 256] = (v1 - mu) * inv * g[tid + 256] + b[tid + 256];
}

// ---------------- Projection GEMM: C[8192,512] = A @ W + bias ----------------
// MODE 0: bf16 K layout [bh][s][64]. MODE 2: bf16 Vt layout [bh][d][s].
// MODE 1: fp32 + residual (final out).
template <int MODE>
__global__ __launch_bounds__(256) void proj_kernel(const float* __restrict__ A,
                                                   const float* __restrict__ W,
                                                   const float* __restrict__ bias,
                                                   const float* __restrict__ resid,
                                                   void* __restrict__ outv) {
    __shared__ float As[8 * 512];
    int tid = threadIdx.x;
    int row0 = blockIdx.x * 8;
    const float* Ab = A + (size_t)row0 * DD;
    for (int idx = tid; idx < 8 * 512; idx += 256) As[idx] = Ab[idx];
    __syncthreads();
    int c0 = tid, c1 = tid + 256;
    float acc0[8], acc1[8];
    float b0 = bias[c0], b1 = bias[c1];
#pragma unroll
    for (int r = 0; r < 8; ++r) { acc0[r] = b0; acc1[r] = b1; }
    for (int k = 0; k < 512; ++k) {
        float w0 = W[(size_t)k * 512 + c0];
        float w1 = W[(size_t)k * 512 + c1];
#pragma unroll
        for (int r = 0; r < 8; ++r) {
            float a = As[r * 512 + k];
            acc0[r] = fmaf(a, w0, acc0[r]);
            acc1[r] = fmaf(a, w1, acc1[r]);
        }
    }
    if (MODE == 0) {
        unsigned short* out = (unsigned short*)outv;
        int b_ = row0 >> 10, s0 = row0 & 1023;
        int h0 = c0 >> 6, d0 = c0 & 63, h1 = c1 >> 6, d1 = c1 & 63;
#pragma unroll
        for (int r = 0; r < 8; ++r) {
            out[((size_t)(b_ * 8 + h0) * 1024 + s0 + r) * 64 + d0] = f2bf(acc0[r]);
            out[((size_t)(b_ * 8 + h1) * 1024 + s0 + r) * 64 + d1] = f2bf(acc1[r]);
        }
    } else if (MODE == 2) {
        unsigned short* out = (unsigned short*)outv;
        int b_ = row0 >> 10, s0 = row0 & 1023;
        int h0 = c0 >> 6, d0 = c0 & 63, h1 = c1 >> 6, d1 = c1 & 63;
        short8 v0, v1;
#pragma unroll
        for (int r = 0; r < 8; ++r) {
            v0[r] = (short)f2bf(acc0[r]);
            v1[r] = (short)f2bf(acc1[r]);
        }
        *reinterpret_cast<short8*>(out + ((size_t)(b_ * 8 + h0) * 64 + d0) * 1024 + s0) = v0;
        *reinterpret_cast<short8*>(out + ((size_t)(b_ * 8 + h1) * 64 + d1) * 1024 + s0) = v1;
    } else {
        float* out = (float*)outv;
#pragma unroll
        for (int r = 0; r < 8; ++r) {
            int R = row0 + r;
            out[(size_t)R * 512 + c0] = acc0[r] + resid[(size_t)R * 512 + c0];
            out[(size_t)R * 512 + c1] = acc1[r] + resid[(size_t)R * 512 + c1];
        }
    }
}

// ---------------- bias table: biasS[q,k] = (pos[q,k,:]@wp + bp) / sqrt(DQ) ----------------
__global__ __launch_bounds__(256) void bias_kernel(const float* __restrict__ pos,
                                                   const float* __restrict__ wp,
                                                   const float* __restrict__ bp,
                                                   float* __restrict__ biasS) {
    int idx = blockIdx.x * 256 + threadIdx.x;  // 0 .. 1048575
    const float4* p4 = (const float4*)(pos + (size_t)idx * 32);
    const float4* w4 = (const float4*)wp;
    float dot = 0.f;
#pragma unroll
    for (int j = 0; j < 8; ++j) {
        float4 pv = p4[j];
        float4 wv = w4[j];
        dot += pv.x * wv.x + pv.y * wv.y + pv.z * wv.z + pv.w * wv.w;
    }
    biasS[idx] = (dot + bp[0]) * 0.125f;
}

// ---------------- transpose biasS[q][k] -> biasT[k][q] ----------------
__global__ __launch_bounds__(256) void transpose_kernel(const float* __restrict__ in,
                                                        float* __restrict__ out) {
    __shared__ float T[64][65];
    int bx = blockIdx.x & 15, by = blockIdx.x >> 4;
    int q0 = by * 64, k0 = bx * 64;
#pragma unroll
    for (int it = 0; it < 16; ++it) {
        int idx = it * 256 + threadIdx.x;
        int r = idx >> 6, col = idx & 63;
        T[r][col] = in[(size_t)(q0 + r) * SS + k0 + col];
    }
    __syncthreads();
#pragma unroll
    for (int it = 0; it < 16; ++it) {
        int idx = it * 256 + threadIdx.x;
        int r = idx >> 6, col = idx & 63;
        out[(size_t)(k0 + r) * SS + q0 + col] = T[col][r];
    }
}

// ---------------- fused MFMA attention ----------------
// grid: 64 bh * 16 qtiles; block 256 = 4 waves * 16 q-rows each.
// K chunks [128][64] bf16 in LDS (XOR swizzle), Vt chunks [64][128] bf16 (XOR swizzle).
// Pass 1: online max/sum per q-row. Pass 2: recompute scores, write probs fp32,
// shfl-pack probs->bf16 into per-wave LDS, MFMA PV.
__global__ __launch_bounds__(256, 2) void attn_kernel(
    const unsigned short* __restrict__ Kg, const unsigned short* __restrict__ Vtg,
    const float* __restrict__ biasT, const float* __restrict__ wp,
    const int* __restrict__ lens, float* __restrict__ probs, float* __restrict__ O) {
    __shared__ __align__(16) char lds[81920];
    char* K0 = lds;                                     // 2 x 16384
    char* V0 = lds + 32768;                             // 2 x 16384
    char* Pm = lds + 65536 + (threadIdx.x >> 6) * 4096; // per-wave 16x128 bf16

    int tid = threadIdx.x;
    int wave = tid >> 6, lane = tid & 63;
    int c = lane & 15, qw = lane >> 4;
    int qt = blockIdx.x & 15, bh = blockIdx.x >> 4;
    int b = bh >> 3, h = bh & 7;
    int len = lens[b];
    int qbw = qt * 64 + wave * 16;
    int q0g = qbw + qw * 4;  // first of this lane's 4 q-rows

    float swp = 0.f;
#pragma unroll
    for (int p = 0; p < 8; ++p) {
        f32x4 w4 = *reinterpret_cast<const f32x4*>(wp + p * 4);
        swp += w4[0] + w4[1] + w4[2] + w4[3];
    }
    const float cscale = swp * 0.044194173824159216f;  // sum(wp)/(sqrt(H)*sqrt(DQ))

    const unsigned short* Kbh = Kg + (size_t)bh * SS * 64;
    const unsigned short* Vbh = Vtg + (size_t)bh * 64 * SS;

    // Q fragments: A[m=q][k=d], lane holds row q = c, d = ds*32 + qw*8 .. +7
    short8 aq[2];
#pragma unroll
    for (int ds = 0; ds < 2; ++ds)
        aq[ds] = *reinterpret_cast<const short8*>(Kbh + (size_t)(qbw + c) * 64 + ds * 32 + qw * 8);

    auto stageK = [&](char* dst, int kbase) {
#pragma unroll
        for (int it = 0; it < 4; ++it) {
            int idx = it * 256 + tid;
            int key = idx >> 3, db = idx & 7;
            uint4 v = *reinterpret_cast<const uint4*>(Kbh + (size_t)(kbase + key) * 64 + db * 8);
            *reinterpret_cast<uint4*>(dst + key * 128 + ((db * 16) ^ ((key & 7) << 4))) = v;
        }
    };
    auto stageV = [&](char* dst, int kbase) {
#pragma unroll
        for (int it = 0; it < 4; ++it) {
            int idx = it * 256 + tid;
            int d = idx >> 4, g = idx & 15;
            uint4 v = *reinterpret_cast<const uint4*>(Vbh + (size_t)d * SS + kbase + g * 8);
            *reinterpret_cast<uint4*>(dst + d * 256 + ((g * 16) ^ ((d & 7) << 4))) = v;
        }
    };

    // scores for one 128-key chunk: sv[f][j] = logit(q = q0g+j, key = kbase + f*16 + c)
    auto scoreChunk = [&](const char* Kb, int kbase, f32x4 sv[8]) {
#pragma unroll
        for (int f = 0; f < 8; ++f) {
            f32x4 acc = {0.f, 0.f, 0.f, 0.f};
            int key = f * 16 + c;
            const char* rowp = Kb + key * 128;
            int sw = (key & 7) << 4;
#pragma unroll
            for (int ds = 0; ds < 2; ++ds) {
                short8 bk = *reinterpret_cast<const short8*>(rowp + ((ds * 64 + qw * 16) ^ sw));
                acc = __builtin_amdgcn_mfma_f32_16x16x32_bf16(aq[ds], bk, acc, 0, 0, 0);
            }
            int kg = kbase + key;
            f32x4 bt = *reinterpret_cast<const f32x4*>(biasT + (size_t)kg * SS + q0g);
            bool ok = kg < len;
#pragma unroll
            for (int j = 0; j < 4; ++j)
                sv[f][j] = ok ? (acc[j] * cscale + bt[j]) : -INFINITY;
        }
    };

    // ---------- pass 1: online m/l ----------
    float m[4], l[4];
#pragma unroll
    for (int j = 0; j < 4; ++j) { m[j] = -INFINITY; l[j] = 0.f; }

    stageK(K0, 0);
    __syncthreads();
#pragma unroll 1
    for (int ch = 0; ch < 8; ++ch) {
        if (ch < 7) stageK(K0 + ((ch + 1) & 1) * 16384, (ch + 1) * 128);
        f32x4 sv[8];
        scoreChunk(K0 + (ch & 1) * 16384, ch * 128, sv);
#pragma unroll
        for (int j = 0; j < 4; ++j) {
            float cm = sv[0][j];
#pragma unroll
            for (int f = 1; f < 8; ++f) cm = fmaxf(cm, sv[f][j]);
            cm = fmaxf(cm, __shfl_xor(cm, 1));
            cm = fmaxf(cm, __shfl_xor(cm, 2));
            cm = fmaxf(cm, __shfl_xor(cm, 4));
            cm = fmaxf(cm, __shfl_xor(cm, 8));
            float mn = fmaxf(m[j], cm);
            float sum = 0.f;
#pragma unroll
            for (int f = 0; f < 8; ++f) sum += __expf(sv[f][j] - mn);
            sum += __shfl_xor(sum, 1);
            sum += __shfl_xor(sum, 2);
            sum += __shfl_xor(sum, 4);
            sum += __shfl_xor(sum, 8);
            l[j] = l[j] * __expf(m[j] - mn) + sum;
            m[j] = mn;
        }
        __syncthreads();
    }

    // ---------- pass 2: probs + PV ----------
    float linv[4];
#pragma unroll
    for (int j = 0; j < 4; ++j) linv[j] = 1.f / l[j];

    stageK(K0, 0);
    stageV(V0, 0);
    __syncthreads();

    f32x4 oacc[4];
#pragma unroll
    for (int nf = 0; nf < 4; ++nf) oacc[nf] = (f32x4){0.f, 0.f, 0.f, 0.f};

    float* probsRow = probs + ((size_t)bh * SS + q0g) * SS;

#pragma unroll 1
    for (int ch = 0; ch < 8; ++ch) {
        if (ch < 7) {
            stageK(K0 + ((ch + 1) & 1) * 16384, (ch + 1) * 128);
            stageV(V0 + ((ch + 1) & 1) * 16384, (ch + 1) * 128);
        }
        f32x4 sv[8];
        scoreChunk(K0 + (ch & 1) * 16384, ch * 128, sv);
        int kbase = ch * 128;
#pragma unroll
        for (int f = 0; f < 8; ++f) {
            int kg = kbase + f * 16 + c;
#pragma unroll
            for (int j = 0; j < 4; ++j) {
                float p = __expf(sv[f][j] - m[j]) * linv[j];
                sv[f][j] = p;
                probsRow[(size_t)j * SS + kg] = p;
            }
        }
        // pack probs -> bf16 into per-wave LDS [16 q][128 k], XOR-swizzled
#pragma unroll
        for (int f = 0; f < 8; ++f) {
            int koff2 = (f * 16 + (c & ~1)) * 2;
#pragma unroll
            for (int j = 0; j < 4; ++j) {
                float my = sv[f][j];
                float ot = __shfl_xor(my, 1);
                float lo = (c & 1) ? ot : my;
                float hi = (c & 1) ? my : ot;
                unsigned w = (unsigned)f2bf(lo) | ((unsigned)f2bf(hi) << 16);
                int q = qw * 4 + j;
                *reinterpret_cast<unsigned*>(Pm + q * 256 + (koff2 ^ ((q & 7) << 4))) = w;
            }
        }
        // PV: O[q][d] += P[q][keys] * V[keys][d]
        const char* Vcur = V0 + (ch & 1) * 16384;
#pragma unroll
        for (int ks = 0; ks < 4; ++ks) {
            short8 pa = *reinterpret_cast<const short8*>(
                Pm + c * 256 + ((ks * 64 + qw * 16) ^ ((c & 7) << 4)));
#pragma unroll
            for (int nf = 0; nf < 4; ++nf) {
                int dr = nf * 16 + c;
                short8 bv = *reinterpret_cast<const short8*>(
                    Vcur + dr * 256 + ((ks * 64 + qw * 16) ^ ((dr & 7) << 4)));
                oacc[nf] = __builtin_amdgcn_mfma_f32_16x16x32_bf16(pa, bv, oacc[nf], 0, 0, 0);
            }
        }
        __syncthreads();
    }

    // O store: [b][s=q][h*64+d]
    float* Obase = O + ((size_t)(b * SS + q0g)) * DD + h * 64;
#pragma unroll
    for (int nf = 0; nf < 4; ++nf)
#pragma unroll
        for (int j = 0; j < 4; ++j)
            Obase[(size_t)j * DD + nf * 16 + c] = oacc[nf][j];
}

extern "C" void kernel_launch(void* const* d_in, const int* in_sizes, int n_in,
                              void* d_out, int out_size, void* d_ws, size_t ws_size,
                              hipStream_t stream) {
    const float* x    = (const float*)d_in[0];
    const float* ln_g = (const float*)d_in[1];
    const float* ln_b = (const float*)d_in[2];
    const float* Wk   = (const float*)d_in[3];
    const float* bk   = (const float*)d_in[4];
    const float* Wv   = (const float*)d_in[5];
    const float* bv   = (const float*)d_in[6];
    const float* pos  = (const float*)d_in[7];
    const float* wp   = (const float*)d_in[8];
    const float* bp   = (const float*)d_in[9];
    const float* Wo   = (const float*)d_in[10];
    const float* bo   = (const float*)d_in[11];
    const int* lens   = (const int*)d_in[12];

    float* out_seq = (float*)d_out;        // 8*1024*512
    float* out_probs = out_seq + 4194304;  // 8*8*1024*1024

    float* ws    = (float*)d_ws;
    float* xn    = ws;                     // 4194304 f32
    float* Obuf  = xn + 4194304;           // 4194304 f32
    float* biasS = Obuf + 4194304;         // 1048576 f32
    float* biasT = biasS + 1048576;        // 1048576 f32
    unsigned short* Kbf  = (unsigned short*)(biasT + 1048576);  // 4194304 bf16
    unsigned short* Vtbf = Kbf + 4194304;                       // 4194304 bf16

    ln_kernel<<<8192, 256, 0, stream>>>(x, ln_g, ln_b, xn);
    proj_kernel<0><<<1024, 256, 0, stream>>>(xn, Wk, bk, nullptr, (void*)Kbf);
    proj_kernel<2><<<1024, 256, 0, stream>>>(xn, Wv, bv, nullptr, (void*)Vtbf);
    bias_kernel<<<4096, 256, 0, stream>>>(pos, wp, bp, biasS);
    transpose_kernel<<<256, 256, 0, stream>>>(biasS, biasT);
    attn_kernel<<<1024, 256, 0, stream>>>(Kbf, Vtbf, biasT, wp, lens, out_probs, Obuf);
    proj_kernel<1><<<1024, 256, 0, stream>>>(Obuf, Wo, bo, x, (void*)out_seq);
}

// Round 3
// 578.865 us; speedup vs baseline: 4.2414x; 1.2710x over previous
//
#include <hip/hip_runtime.h>
#include <hip/hip_bf16.h>
#include <math.h>

typedef __attribute__((ext_vector_type(8))) short short8;
typedef __attribute__((ext_vector_type(4))) float f32x4;

#define SS 1024
#define DD 512
#define HH 8

__device__ __forceinline__ unsigned short f2bf(float f) {
    unsigned u; __builtin_memcpy(&u, &f, 4);
    u = (u + 0x7FFFu + ((u >> 16) & 1u)) >> 16;
    return (unsigned short)u;
}

// ---------------- LayerNorm -> bf16 ----------------
__global__ __launch_bounds__(256) void ln_kernel(const float* __restrict__ x,
                                                 const float* __restrict__ g,
                                                 const float* __restrict__ b,
                                                 unsigned short* __restrict__ xnb) {
    int row = blockIdx.x;
    int tid = threadIdx.x;
    const float* xr = x + (size_t)row * DD;
    float v0 = xr[tid], v1 = xr[tid + 256];
    float s = v0 + v1;
    float ss = v0 * v0 + v1 * v1;
    for (int off = 32; off; off >>= 1) {
        s += __shfl_down(s, off);
        ss += __shfl_down(ss, off);
    }
    __shared__ float ps[4], pss[4];
    int wid = tid >> 6, lane = tid & 63;
    if (lane == 0) { ps[wid] = s; pss[wid] = ss; }
    __syncthreads();
    float tot_s = ps[0] + ps[1] + ps[2] + ps[3];
    float tot_ss = pss[0] + pss[1] + pss[2] + pss[3];
    float mu = tot_s * (1.0f / DD);
    float var = tot_ss * (1.0f / DD) - mu * mu;
    float inv = rsqrtf(var + 1e-5f);
    unsigned short* xo = xnb + (size_t)row * DD;
    xo[tid] = f2bf((v0 - mu) * inv * g[tid] + b[tid]);
    xo[tid + 256] = f2bf((v1 - mu) * inv * g[tid + 256] + b[tid + 256]);
}

// ---------------- W[k][n] f32 -> Wt[n][k] bf16 ----------------
__global__ __launch_bounds__(256) void wt_kernel(const float* __restrict__ W,
                                                 unsigned short* __restrict__ Wt) {
    __shared__ float T[64][65];
    int bx = blockIdx.x & 7, by = blockIdx.x >> 3;
    int k0 = by * 64, n0 = bx * 64;
#pragma unroll
    for (int it = 0; it < 16; ++it) {
        int idx = it * 256 + threadIdx.x;
        int r = idx >> 6, cc = idx & 63;
        T[r][cc] = W[(size_t)(k0 + r) * DD + n0 + cc];
    }
    __syncthreads();
#pragma unroll
    for (int it = 0; it < 16; ++it) {
        int idx = it * 256 + threadIdx.x;
        int r = idx >> 6, cc = idx & 63;
        Wt[(size_t)(n0 + r) * DD + k0 + cc] = f2bf(T[cc][r]);
    }
}

// ---------------- bias table: biasS[q,k] = (pos[q,k,:]@wp + bp) / sqrt(DQ) ----------------
__global__ __launch_bounds__(256) void bias_kernel(const float* __restrict__ pos,
                                                   const float* __restrict__ wp,
                                                   const float* __restrict__ bp,
                                                   float* __restrict__ biasS) {
    int idx = blockIdx.x * 256 + threadIdx.x;
    const float4* p4 = (const float4*)(pos + (size_t)idx * 32);
    const float4* w4 = (const float4*)wp;
    float dot = 0.f;
#pragma unroll
    for (int j = 0; j < 8; ++j) {
        float4 pv = p4[j];
        float4 wv = w4[j];
        dot += pv.x * wv.x + pv.y * wv.y + pv.z * wv.z + pv.w * wv.w;
    }
    biasS[idx] = (dot + bp[0]) * 0.125f;
}

// ---------------- MFMA GEMM: C[8192,512] = A_bf16 @ Wt_bf16^T + bias ----------------
// 64x128 tile, BK=64, 4 waves (2m x 2n), each wave 32x64.
// MODE 0: K layout [bh][s][64] bf16. MODE 1: Vt layout [bh][d][s] bf16. MODE 2: f32 + resid.
template <int MODE>
__global__ __launch_bounds__(256, 2) void gemm_kernel(
    const unsigned short* __restrict__ A, const unsigned short* __restrict__ Bt,
    const float* __restrict__ bias, const float* __restrict__ resid,
    void* __restrict__ outv) {
    __shared__ __align__(16) char lds[49152];
    int tid = threadIdx.x;
    int wave = tid >> 6, lane = tid & 63;
    int c = lane & 15, qw = lane >> 4;
    int bm = blockIdx.x >> 2, bn = blockIdx.x & 3;
    int m0 = bm * 64, n0 = bn * 128;
    int wm = wave >> 1, wn = wave & 1;

    // load indices (fixed per thread)
    int ra = tid >> 3, ga = tid & 7;           // A: it*32 rows per pass? A rows: idx>>3
    uint4 regA[2], regB[4];

    auto gload = [&](int k0) {
#pragma unroll
        for (int it = 0; it < 2; ++it) {
            int idx = it * 256 + tid;
            int r = idx >> 3, g = idx & 7;
            regA[it] = *reinterpret_cast<const uint4*>(A + (size_t)(m0 + r) * DD + k0 + g * 8);
        }
#pragma unroll
        for (int it = 0; it < 4; ++it) {
            int idx = it * 256 + tid;
            int r = idx >> 3, g = idx & 7;
            regB[it] = *reinterpret_cast<const uint4*>(Bt + (size_t)(n0 + r) * DD + k0 + g * 8);
        }
    };
    auto lwrite = [&](char* dst) {
        char* Ad = dst;
        char* Bd = dst + 8192;
#pragma unroll
        for (int it = 0; it < 2; ++it) {
            int idx = it * 256 + tid;
            int r = idx >> 3, g = idx & 7;
            *reinterpret_cast<uint4*>(Ad + r * 128 + ((g * 16) ^ ((r & 7) << 4))) = regA[it];
        }
#pragma unroll
        for (int it = 0; it < 4; ++it) {
            int idx = it * 256 + tid;
            int r = idx >> 3, g = idx & 7;
            *reinterpret_cast<uint4*>(Bd + r * 128 + ((g * 16) ^ ((r & 7) << 4))) = regB[it];
        }
    };

    f32x4 acc[2][4];
#pragma unroll
    for (int mf = 0; mf < 2; ++mf)
#pragma unroll
        for (int nf = 0; nf < 4; ++nf) acc[mf][nf] = (f32x4){0.f, 0.f, 0.f, 0.f};

    gload(0);
    lwrite(lds);
    __syncthreads();

    int sw = (c & 7) << 4;
#pragma unroll 1
    for (int kk = 0; kk < 8; ++kk) {
        if (kk < 7) gload((kk + 1) * 64);
        const char* cur = lds + (kk & 1) * 24576;
        const char* Asw = cur;
        const char* Bsw = cur + 8192;
#pragma unroll
        for (int ks = 0; ks < 2; ++ks) {
            int off = (ks * 64 + qw * 16) ^ sw;
            short8 af[2], bf[4];
#pragma unroll
            for (int mf = 0; mf < 2; ++mf)
                af[mf] = *reinterpret_cast<const short8*>(Asw + (wm * 32 + mf * 16 + c) * 128 + off);
#pragma unroll
            for (int nf = 0; nf < 4; ++nf)
                bf[nf] = *reinterpret_cast<const short8*>(Bsw + (wn * 64 + nf * 16 + c) * 128 + off);
#pragma unroll
            for (int mf = 0; mf < 2; ++mf)
#pragma unroll
                for (int nf = 0; nf < 4; ++nf)
                    acc[mf][nf] = __builtin_amdgcn_mfma_f32_16x16x32_bf16(af[mf], bf[nf], acc[mf][nf], 0, 0, 0);
        }
        if (kk < 7) lwrite(lds + ((kk + 1) & 1) * 24576);
        __syncthreads();
    }

    float bias_n[4];
#pragma unroll
    for (int nf = 0; nf < 4; ++nf) bias_n[nf] = bias[n0 + wn * 64 + nf * 16 + c];

    if (MODE == 0) {
        unsigned short* out = (unsigned short*)outv;
        int b_ = m0 >> 10;
#pragma unroll
        for (int mf = 0; mf < 2; ++mf)
#pragma unroll
            for (int nf = 0; nf < 4; ++nf) {
                int n = n0 + wn * 64 + nf * 16 + c;
                int h = n >> 6, d = n & 63;
#pragma unroll
                for (int j = 0; j < 4; ++j) {
                    int s = (m0 & 1023) + wm * 32 + mf * 16 + qw * 4 + j;
                    out[((size_t)(b_ * 8 + h) * 1024 + s) * 64 + d] = f2bf(acc[mf][nf][j] + bias_n[nf]);
                }
            }
    } else if (MODE == 1) {
        unsigned short* out = (unsigned short*)outv;
        int b_ = m0 >> 10;
#pragma unroll
        for (int mf = 0; mf < 2; ++mf)
#pragma unroll
            for (int nf = 0; nf < 4; ++nf) {
                int n = n0 + wn * 64 + nf * 16 + c;
                int h = n >> 6, d = n & 63;
                int s0 = (m0 & 1023) + wm * 32 + mf * 16 + qw * 4;
                uint2 z;
                z.x = (unsigned)f2bf(acc[mf][nf][0] + bias_n[nf]) |
                      ((unsigned)f2bf(acc[mf][nf][1] + bias_n[nf]) << 16);
                z.y = (unsigned)f2bf(acc[mf][nf][2] + bias_n[nf]) |
                      ((unsigned)f2bf(acc[mf][nf][3] + bias_n[nf]) << 16);
                *reinterpret_cast<uint2*>(out + ((size_t)(b_ * 8 + h) * 64 + d) * 1024 + s0) = z;
            }
    } else {
        float* out = (float*)outv;
#pragma unroll
        for (int mf = 0; mf < 2; ++mf)
#pragma unroll
            for (int nf = 0; nf < 4; ++nf) {
                int n = n0 + wn * 64 + nf * 16 + c;
#pragma unroll
                for (int j = 0; j < 4; ++j) {
                    int mg = m0 + wm * 32 + mf * 16 + qw * 4 + j;
                    out[(size_t)mg * DD + n] = acc[mf][nf][j] + bias_n[nf] + resid[(size_t)mg * DD + n];
                }
            }
    }
}

// ---------------- fused MFMA attention (swapped QK: D[m=key][n=q]) ----------------
__global__ __launch_bounds__(256, 2) void attn_kernel(
    const unsigned short* __restrict__ Kg, const unsigned short* __restrict__ Vtg,
    const float* __restrict__ biasS, const float* __restrict__ wp,
    const int* __restrict__ lens, float* __restrict__ probs,
    unsigned short* __restrict__ Obf) {
    __shared__ __align__(16) char lds[81920];
    char* Kbuf = lds;                                    // 2 x 16384
    char* Vbuf = lds + 32768;                            // 2 x 16384
    char* Pm = lds + 65536 + (threadIdx.x >> 6) * 4096;  // per-wave 16q x 128k bf16

    int tid = threadIdx.x;
    int wave = tid >> 6, lane = tid & 63;
    int c = lane & 15, qw = lane >> 4;
    int qt = blockIdx.x & 15, bh = blockIdx.x >> 4;
    int b = bh >> 3, h = bh & 7;
    int len = lens[b];
    int nact = (len + 127) >> 7;  // 4..8 active chunks
    int qbw = qt * 64 + wave * 16;
    int qg = qbw + c;  // this lane's q for scores/softmax/probs

    float swp = 0.f;
#pragma unroll
    for (int p = 0; p < 8; ++p) {
        f32x4 w4 = *reinterpret_cast<const f32x4*>(wp + p * 4);
        swp += w4[0] + w4[1] + w4[2] + w4[3];
    }
    const float cscale = swp * 0.044194173824159216f;  // sum(wp)/(sqrt(H)*sqrt(DQ))

    const unsigned short* Kbh = Kg + (size_t)bh * SS * 64;
    const unsigned short* Vbh = Vtg + (size_t)bh * 64 * SS;

    // Q as B operand: lane c holds Q row qbw+c, k-octet qw
    short8 bq[2];
#pragma unroll
    for (int ds = 0; ds < 2; ++ds)
        bq[ds] = *reinterpret_cast<const short8*>(Kbh + (size_t)(qbw + c) * 64 + ds * 32 + qw * 8);

    auto stageK = [&](char* dst, int kbase) {
#pragma unroll
        for (int it = 0; it < 4; ++it) {
            int idx = it * 256 + tid;
            int key = idx >> 3, db = idx & 7;
            uint4 v = *reinterpret_cast<const uint4*>(Kbh + (size_t)(kbase + key) * 64 + db * 8);
            *reinterpret_cast<uint4*>(dst + key * 128 + ((db * 16) ^ ((key & 7) << 4))) = v;
        }
    };
    auto stageV = [&](char* dst, int kbase) {
#pragma unroll
        for (int it = 0; it < 4; ++it) {
            int idx = it * 256 + tid;
            int d = idx >> 4, g = idx & 15;
            uint4 v = *reinterpret_cast<const uint4*>(Vbh + (size_t)d * SS + kbase + g * 8);
            *reinterpret_cast<uint4*>(dst + d * 256 + ((g * 16) ^ ((d & 7) << 4))) = v;
        }
    };

    int swc = (c & 7) << 4;
    // scores: sv[f][j] = logit(key = kbase+f*16+qw*4+j, q = qg)
    auto scoreChunk = [&](const char* Kb, int kbase, f32x4 sv[8]) {
#pragma unroll
        for (int f = 0; f < 8; ++f) {
            f32x4 acc = {0.f, 0.f, 0.f, 0.f};
            const char* rowp = Kb + (f * 16 + c) * 128;
#pragma unroll
            for (int ds = 0; ds < 2; ++ds) {
                short8 kf = *reinterpret_cast<const short8*>(rowp + ((ds * 64 + qw * 16) ^ swc));
                acc = __builtin_amdgcn_mfma_f32_16x16x32_bf16(kf, bq[ds], acc, 0, 0, 0);
            }
            int kb4 = kbase + f * 16 + qw * 4;
            f32x4 bt = *reinterpret_cast<const f32x4*>(biasS + (size_t)qg * SS + kb4);
#pragma unroll
            for (int j = 0; j < 4; ++j)
                sv[f][j] = (kb4 + j < len) ? (acc[j] * cscale + bt[j]) : -INFINITY;
        }
    };

    // ---------- pass 1: running m, l (per lane; q = qg) ----------
    float m_s = -INFINITY, l_s = 0.f;
    stageK(Kbuf, 0);
    __syncthreads();
#pragma unroll 1
    for (int ch = 0; ch < nact; ++ch) {
        if (ch + 1 < nact) stageK(Kbuf + ((ch + 1) & 1) * 16384, (ch + 1) * 128);
        f32x4 sv[8];
        scoreChunk(Kbuf + (ch & 1) * 16384, ch * 128, sv);
        float cm = sv[0][0];
#pragma unroll
        for (int f = 0; f < 8; ++f)
#pragma unroll
            for (int j = 0; j < 4; ++j) cm = fmaxf(cm, sv[f][j]);
        cm = fmaxf(cm, __shfl_xor(cm, 16));
        cm = fmaxf(cm, __shfl_xor(cm, 32));
        float mn = fmaxf(m_s, cm);
        float sum = 0.f;
#pragma unroll
        for (int f = 0; f < 8; ++f)
#pragma unroll
            for (int j = 0; j < 4; ++j) sum += __expf(sv[f][j] - mn);
        sum += __shfl_xor(sum, 16);
        sum += __shfl_xor(sum, 32);
        l_s = l_s * __expf(m_s - mn) + sum;
        m_s = mn;
        __syncthreads();
    }

    // ---------- pass 2: probs + PV ----------
    float linv = 1.f / l_s;
    stageK(Kbuf, 0);
    stageV(Vbuf, 0);
    __syncthreads();

    f32x4 oacc[4];
#pragma unroll
    for (int nf = 0; nf < 4; ++nf) oacc[nf] = (f32x4){0.f, 0.f, 0.f, 0.f};

    float* probsRow = probs + ((size_t)bh * SS + qg) * SS;

#pragma unroll 1
    for (int ch = 0; ch < nact; ++ch) {
        if (ch + 1 < nact) {
            stageK(Kbuf + ((ch + 1) & 1) * 16384, (ch + 1) * 128);
            stageV(Vbuf + ((ch + 1) & 1) * 16384, (ch + 1) * 128);
        }
        f32x4 sv[8];
        scoreChunk(Kbuf + (ch & 1) * 16384, ch * 128, sv);
#pragma unroll
        for (int f = 0; f < 8; ++f) {
            f32x4 pv;
#pragma unroll
            for (int j = 0; j < 4; ++j) pv[j] = __expf(sv[f][j] - m_s) * linv;
            *reinterpret_cast<f32x4*>(probsRow + ch * 128 + f * 16 + qw * 4) = pv;
            uint2 z;
            z.x = (unsigned)f2bf(pv[0]) | ((unsigned)f2bf(pv[1]) << 16);
            z.y = (unsigned)f2bf(pv[2]) | ((unsigned)f2bf(pv[3]) << 16);
            *reinterpret_cast<uint2*>(Pm + c * 256 + ((f * 32 + qw * 8) ^ swc)) = z;
        }
        // PV: O[q][d] += P[q][k] V[k][d]
        const char* Vcur = Vbuf + (ch & 1) * 16384;
#pragma unroll
        for (int ks = 0; ks < 4; ++ks) {
            short8 pa = *reinterpret_cast<const short8*>(Pm + c * 256 + (((ks * 64 + qw * 16)) ^ swc));
#pragma unroll
            for (int nf = 0; nf < 4; ++nf) {
                int dr = nf * 16 + c;
                short8 bv = *reinterpret_cast<const short8*>(
                    Vcur + dr * 256 + ((ks * 64 + qw * 16) ^ ((dr & 7) << 4)));
                oacc[nf] = __builtin_amdgcn_mfma_f32_16x16x32_bf16(pa, bv, oacc[nf], 0, 0, 0);
            }
        }
        __syncthreads();
    }

    // zero-fill probs for fully-masked chunks
    f32x4 zv = {0.f, 0.f, 0.f, 0.f};
#pragma unroll 1
    for (int ch = nact; ch < 8; ++ch)
#pragma unroll
        for (int f = 0; f < 8; ++f)
            *reinterpret_cast<f32x4*>(probsRow + ch * 128 + f * 16 + qw * 4) = zv;

    // O store bf16: rows q = qbw + qw*4 + j, cols h*64 + nf*16 + c
    unsigned short* Ob = Obf + ((size_t)(b * SS + qbw + qw * 4)) * DD + h * 64;
#pragma unroll
    for (int nf = 0; nf < 4; ++nf)
#pragma unroll
        for (int j = 0; j < 4; ++j)
            Ob[(size_t)j * DD + nf * 16 + c] = f2bf(oacc[nf][j]);
}

extern "C" void kernel_launch(void* const* d_in, const int* in_sizes, int n_in,
                              void* d_out, int out_size, void* d_ws, size_t ws_size,
                              hipStream_t stream) {
    const float* x    = (const float*)d_in[0];
    const float* ln_g = (const float*)d_in[1];
    const float* ln_b = (const float*)d_in[2];
    const float* Wk   = (const float*)d_in[3];
    const float* bk   = (const float*)d_in[4];
    const float* Wv   = (const float*)d_in[5];
    const float* bv   = (const float*)d_in[6];
    const float* pos  = (const float*)d_in[7];
    const float* wp   = (const float*)d_in[8];
    const float* bp   = (const float*)d_in[9];
    const float* Wo   = (const float*)d_in[10];
    const float* bo   = (const float*)d_in[11];
    const int* lens   = (const int*)d_in[12];

    float* out_seq = (float*)d_out;        // 8*1024*512 f32
    float* out_probs = out_seq + 4194304;  // 8*8*1024*1024 f32

    float* ws = (float*)d_ws;
    float* biasS = ws;                                     // 1048576 f32
    unsigned short* xnb  = (unsigned short*)(biasS + 1048576);  // 4194304 bf16
    unsigned short* Wkt  = xnb + 4194304;                  // 262144 bf16
    unsigned short* Wvt  = Wkt + 262144;
    unsigned short* Wot  = Wvt + 262144;
    unsigned short* Kbf  = Wot + 262144;                   // 4194304 bf16
    unsigned short* Vtbf = Kbf + 4194304;                  // 4194304 bf16
    unsigned short* Obf  = Vtbf + 4194304;                 // 4194304 bf16

    ln_kernel<<<8192, 256, 0, stream>>>(x, ln_g, ln_b, xnb);
    wt_kernel<<<64, 256, 0, stream>>>(Wk, Wkt);
    wt_kernel<<<64, 256, 0, stream>>>(Wv, Wvt);
    wt_kernel<<<64, 256, 0, stream>>>(Wo, Wot);
    bias_kernel<<<4096, 256, 0, stream>>>(pos, wp, bp, biasS);
    gemm_kernel<0><<<512, 256, 0, stream>>>(xnb, Wkt, bk, nullptr, (void*)Kbf);
    gemm_kernel<1><<<512, 256, 0, stream>>>(xnb, Wvt, bv, nullptr, (void*)Vtbf);
    attn_kernel<<<1024, 256, 0, stream>>>(Kbf, Vtbf, biasS, wp, lens, out_probs, Obf);
    gemm_kernel<2><<<512, 256, 0, stream>>>(Obf, Wot, bo, x, (void*)out_seq);
}